// Round 2
// baseline (737.642 us; speedup 1.0000x reference)
//
#include <hip/hip_runtime.h>

typedef short short8 __attribute__((ext_vector_type(8)));
typedef short short4v __attribute__((ext_vector_type(4)));
typedef float f32x4 __attribute__((ext_vector_type(4)));
typedef float float4v __attribute__((ext_vector_type(4)));

__device__ __forceinline__ unsigned short f2bf(float f) {
  unsigned u = __float_as_uint(f);
  u += 0x7FFFu + ((u >> 16) & 1u);
  return (unsigned short)(u >> 16);
}
__device__ __forceinline__ float b2f(short s) {
  return __uint_as_float(((unsigned)(unsigned short)s) << 16);
}

__device__ __forceinline__ f32x4 mfma16(short8 a, short8 b, f32x4 c) {
  return __builtin_amdgcn_mfma_f32_16x16x32_bf16(a, b, c, 0, 0, 0);
}

#define GLOAD16(g, l) __builtin_amdgcn_global_load_lds( \
    (const __attribute__((address_space(1))) unsigned int*)(g), \
    (__attribute__((address_space(3))) unsigned int*)(l), 16, 0, 0)

// ---------------- convert x: fp32 -> bf16 ----------------
__global__ void convert_kernel(const float* __restrict__ in,
                               unsigned short* __restrict__ out, int n4) {
  int stride = gridDim.x * blockDim.x;
  for (int i = blockIdx.x * blockDim.x + threadIdx.x; i < n4; i += stride) {
    float4v v = *(const float4v*)(in + 4l * i);
    short4v o;
#pragma unroll
    for (int j = 0; j < 4; ++j) o[j] = (short)f2bf(v[j]);
    *(short4v*)(out + 4l * i) = o;
  }
}

// ------- transpose + convert weights: in[K=1024][N] -> out[N][1024] -------
__global__ void transpose_conv_kernel(const float* __restrict__ in,
                                      unsigned short* __restrict__ out, int N) {
  int total = N << 10;
  int stride = gridDim.x * blockDim.x;
  for (int idx = blockIdx.x * blockDim.x + threadIdx.x; idx < total; idx += stride) {
    int n = idx >> 10;
    int k = idx & 1023;
    out[idx] = f2bf(in[(long)k * N + n]);
  }
}

// ---------------- RoPE table: cos/sin[t][d], repeated pairs ----------------
__global__ void rope_table_kernel(float* __restrict__ cosT, float* __restrict__ sinT) {
  int i = blockIdx.x * 64 + threadIdx.x;  // 4096 = 64*64
  int t = i >> 6, d = i & 63;
  int j = d >> 1;
  float inv = powf(10000.0f, -(float)(2 * j) / 64.0f);
  float ang = (float)t * inv;
  cosT[i] = cosf(ang);
  sinT[i] = sinf(ang);
}

// ---------------- 128x128 bf16 GEMM (m97 structure) ----------------
// A[M][K] bf16 row-major, Bt[N][K] bf16 (i.e. B^T), K multiple of 32.
// MODE 0: C bf16 [M][N].  MODE 1: C fp32 [M][N] += bias[n].
template <int MODE>
__global__ __launch_bounds__(256) void gemm_kernel(
    const unsigned short* __restrict__ A, const unsigned short* __restrict__ Bt,
    void* __restrict__ Cv, const float* __restrict__ bias,
    int M, int N, int K, int ntn) {
  __shared__ unsigned short As[128 * 32];
  __shared__ unsigned short Bs[128 * 32];
  const int t = threadIdx.x;
  const int l = t & 63;
  const int lg = l >> 4, lm = l & 15;
  const int w = t >> 6;
  const int wm = w >> 1, wn = w & 1;
  const int tm = blockIdx.x / ntn, tn = blockIdx.x % ntn;
  const int srow = t >> 2, scol = (t & 3) << 3;
  const unsigned short* ag = A + (long)(tm * 128 + srow) * K + scol;
  const unsigned short* bg = Bt + (long)(tn * 128 + srow) * K + scol;
  unsigned short* asl = As + srow * 32 + scol;
  unsigned short* bsl = Bs + srow * 32 + scol;
  f32x4 acc[4][4] = {};

  for (int k0 = 0; k0 < K; k0 += 32) {
    __syncthreads();
    GLOAD16(ag + k0, asl);
    GLOAD16(ag + (long)64 * K + k0, asl + 64 * 32);
    GLOAD16(bg + k0, bsl);
    GLOAD16(bg + (long)64 * K + k0, bsl + 64 * 32);
    asm volatile("s_waitcnt vmcnt(0)" ::: "memory");
    __syncthreads();
    short8 af[4], bf[4];
#pragma unroll
    for (int mi = 0; mi < 4; ++mi)
      af[mi] = *(const short8*)(As + (wm * 64 + mi * 16 + lm) * 32 + lg * 8);
#pragma unroll
    for (int ni = 0; ni < 4; ++ni)
      bf[ni] = *(const short8*)(Bs + (wn * 64 + ni * 16 + lm) * 32 + lg * 8);
#pragma unroll
    for (int mi = 0; mi < 4; ++mi)
#pragma unroll
      for (int ni = 0; ni < 4; ++ni)
        acc[mi][ni] = mfma16(af[mi], bf[ni], acc[mi][ni]);
  }

  const long row0 = (long)tm * 128 + wm * 64;
  const int col0 = tn * 128 + wn * 64;
  if (MODE == 0) {
    unsigned short* C = (unsigned short*)Cv;
#pragma unroll
    for (int mi = 0; mi < 4; ++mi)
#pragma unroll
      for (int ni = 0; ni < 4; ++ni) {
        long r0 = row0 + mi * 16 + lg * 4;
        int c = col0 + ni * 16 + lm;
#pragma unroll
        for (int r = 0; r < 4; ++r)
          C[(r0 + r) * N + c] = f2bf(acc[mi][ni][r]);
      }
  } else {
    float* C = (float*)Cv;
#pragma unroll
    for (int mi = 0; mi < 4; ++mi)
#pragma unroll
      for (int ni = 0; ni < 4; ++ni) {
        long r0 = row0 + mi * 16 + lg * 4;
        int c = col0 + ni * 16 + lm;
        float bv = bias[c];
#pragma unroll
        for (int r = 0; r < 4; ++r)
          C[(r0 + r) * N + c] = acc[mi][ni][r] + bv;
      }
  }
}

// ---------------- attention: one wave per (b,h,w,head) ----------------
// qkv bf16 [32768][3072] rows m = ((b*64+t)*16+h)*16+w; cols q|k|v each 1024.
// attn_out bf16 [32768][1024], col = head*64 + dh.
__global__ __launch_bounds__(64) void attn_kernel(
    const unsigned short* __restrict__ qkv,
    const float* __restrict__ cosT, const float* __restrict__ sinT,
    unsigned short* __restrict__ attn_out) {
  __shared__ unsigned short Vt[64 * 72];  // [dh][s], padded
  __shared__ unsigned short Pl[64 * 72];  // [t][s],  padded
  const int l = threadIdx.x;
  const int lg = l >> 4, lm = l & 15;
  const int bid = blockIdx.x;
  const int head = bid & 15, wq = (bid >> 4) & 15, hq = (bid >> 8) & 15, b = bid >> 12;
  const long base_m = (long)b * 64 * 256 + hq * 16 + wq;  // m(t) = base_m + t*256
  const int qcol = head * 64, kcol = 1024 + head * 64, vcol = 2048 + head * 64;

  // ---- stage V transposed into LDS ----
  {
    const int sr = l >> 3;
    const int c8 = (l & 7) * 8;
#pragma unroll
    for (int p = 0; p < 8; ++p) {
      int s = p * 8 + sr;
      short8 v = *(const short8*)(qkv + (base_m + (long)s * 256) * 3072 + vcol + c8);
#pragma unroll
      for (int i = 0; i < 8; ++i)
        Vt[(c8 + i) * 72 + s] = (unsigned short)v[i];
    }
  }

  // ---- load Q,K fragments with RoPE in-register ----
  short8 qf[4][2], kf[4][2];
#pragma unroll
  for (int ti = 0; ti < 4; ++ti)
#pragma unroll
    for (int ks = 0; ks < 2; ++ks) {
      int t = ti * 16 + lm;
      int d0 = ks * 32 + lg * 8;
      short8 rawq = *(const short8*)(qkv + (base_m + (long)t * 256) * 3072 + qcol + d0);
      short8 rawk = *(const short8*)(qkv + (base_m + (long)t * 256) * 3072 + kcol + d0);
      short8 oq, ok;
#pragma unroll
      for (int p = 0; p < 4; ++p) {
        float c = cosT[t * 64 + d0 + 2 * p];
        float s = sinT[t * 64 + d0 + 2 * p];
        float e = b2f(rawq[2 * p]), o = b2f(rawq[2 * p + 1]);
        oq[2 * p] = (short)f2bf(e * c - o * s);
        oq[2 * p + 1] = (short)f2bf(o * c + e * s);
        e = b2f(rawk[2 * p]); o = b2f(rawk[2 * p + 1]);
        ok[2 * p] = (short)f2bf(e * c - o * s);
        ok[2 * p + 1] = (short)f2bf(o * c + e * s);
      }
      qf[ti][ks] = oq;
      kf[ti][ks] = ok;
    }

  // ---- S^T = K Q^T : frag [si][ti], lane holds S[s=16si+4lg+r][t=16ti+lm] ----
  f32x4 sT[4][4];
#pragma unroll
  for (int si = 0; si < 4; ++si)
#pragma unroll
    for (int ti = 0; ti < 4; ++ti) {
      f32x4 a = {0.f, 0.f, 0.f, 0.f};
      a = mfma16(kf[si][0], qf[ti][0], a);
      a = mfma16(kf[si][1], qf[ti][1], a);
      sT[si][ti] = a;
    }

  // ---- causal mask + softmax over s (per column t) ----
#pragma unroll
  for (int ti = 0; ti < 4; ++ti) {
    const int t = ti * 16 + lm;
    float mx = -1e30f;
#pragma unroll
    for (int si = 0; si < 4; ++si)
#pragma unroll
      for (int r = 0; r < 4; ++r) {
        int s = si * 16 + lg * 4 + r;
        float v = sT[si][ti][r] * 0.125f;
        v = (s <= t) ? v : -1e30f;
        sT[si][ti][r] = v;
        mx = fmaxf(mx, v);
      }
    mx = fmaxf(mx, __shfl_xor(mx, 16));
    mx = fmaxf(mx, __shfl_xor(mx, 32));
    float sum = 0.f;
#pragma unroll
    for (int si = 0; si < 4; ++si)
#pragma unroll
      for (int r = 0; r < 4; ++r) {
        float e = __expf(sT[si][ti][r] - mx);
        sT[si][ti][r] = e;
        sum += e;
      }
    sum += __shfl_xor(sum, 16);
    sum += __shfl_xor(sum, 32);
    float inv = 1.0f / sum;
#pragma unroll
    for (int si = 0; si < 4; ++si) {
      short4v pk;
#pragma unroll
      for (int r = 0; r < 4; ++r) pk[r] = (short)f2bf(sT[si][ti][r] * inv);
      *(short4v*)(Pl + t * 72 + si * 16 + lg * 4) = pk;
    }
  }

  __syncthreads();

  // ---- O = P V : frags [mi][ni] over t, dh ----
  f32x4 o[4][4] = {};
#pragma unroll
  for (int ks = 0; ks < 2; ++ks) {
    short8 pa[4], vb[4];
#pragma unroll
    for (int mi = 0; mi < 4; ++mi)
      pa[mi] = *(const short8*)(Pl + (mi * 16 + lm) * 72 + ks * 32 + lg * 8);
#pragma unroll
    for (int ni = 0; ni < 4; ++ni)
      vb[ni] = *(const short8*)(Vt + (ni * 16 + lm) * 72 + ks * 32 + lg * 8);
#pragma unroll
    for (int mi = 0; mi < 4; ++mi)
#pragma unroll
      for (int ni = 0; ni < 4; ++ni)
        o[mi][ni] = mfma16(pa[mi], vb[ni], o[mi][ni]);
  }

  // ---- write O (bf16) ----
#pragma unroll
  for (int mi = 0; mi < 4; ++mi)
#pragma unroll
    for (int ni = 0; ni < 4; ++ni) {
      int dh = ni * 16 + lm;
#pragma unroll
      for (int r = 0; r < 4; ++r) {
        int t = mi * 16 + lg * 4 + r;
        attn_out[(base_m + (long)t * 256) * 1024 + head * 64 + dh] = f2bf(o[mi][ni][r]);
      }
    }
}

extern "C" void kernel_launch(void* const* d_in, const int* in_sizes, int n_in,
                              void* d_out, int out_size, void* d_ws, size_t ws_size,
                              hipStream_t stream) {
  const float* x = (const float*)d_in[0];       // [2,64,16,16,1024]
  const float* w_qkv = (const float*)d_in[1];   // [1024,3072]
  const float* w_out = (const float*)d_in[2];   // [1024,1024]
  const float* b_out = (const float*)d_in[3];   // [1024]
  float* out = (float*)d_out;                   // [32768,1024] fp32

  char* ws = (char*)d_ws;
  size_t off = 0;
  auto carve = [&](size_t bytes) {
    void* p = ws + off;
    off = (off + bytes + 255) & ~(size_t)255;
    return p;
  };
  const long M = 32768;
  unsigned short* Xb  = (unsigned short*)carve(M * 1024 * 2);  // x bf16; reused as attn_out
  unsigned short* Wq  = (unsigned short*)carve(3072 * 1024 * 2);
  unsigned short* Wo  = (unsigned short*)carve(1024 * 1024 * 2);
  float* cosT = (float*)carve(64 * 64 * 4);
  float* sinT = (float*)carve(64 * 64 * 4);
  unsigned short* Qkv = (unsigned short*)carve(M * 3072 * 2);

  convert_kernel<<<4096, 256, 0, stream>>>(x, Xb, (int)(M * 1024 / 4));
  transpose_conv_kernel<<<3072, 256, 0, stream>>>(w_qkv, Wq, 3072);
  transpose_conv_kernel<<<1024, 256, 0, stream>>>(w_out, Wo, 1024);
  rope_table_kernel<<<64, 64, 0, stream>>>(cosT, sinT);

  gemm_kernel<0><<<256 * 24, 256, 0, stream>>>(Xb, Wq, (void*)Qkv, nullptr,
                                               (int)M, 3072, 1024, 24);
  attn_kernel<<<8192, 64, 0, stream>>>(Qkv, cosT, sinT, Xb);
  gemm_kernel<1><<<256 * 8, 256, 0, stream>>>(Xb, Wo, (void*)out, b_out,
                                              (int)M, 1024, 1024, 8);
}